// Round 2
// baseline (82.002 us; speedup 1.0000x reference)
//
#include <hip/hip_runtime.h>

#define NB 512
#define NN 1000
#define ND 128
#define NS 8

static constexpr float NORM = 0.088388347648318447f; // 1/sqrt(128)

__device__ __forceinline__ float red32(float v) {
#pragma unroll
    for (int m = 1; m <= 16; m <<= 1)
        v += __shfl_xor(v, m, 64);
    return v;
}

__global__ __launch_bounds__(256, 2)
void attn_edge_kernel(const float* __restrict__ node_emb,
                      const float* __restrict__ state,
                      const int* __restrict__ curr_id,
                      const int* __restrict__ next_id,
                      const int* __restrict__ mask,
                      const float* __restrict__ w_q,
                      const float* __restrict__ w_k,
                      const float* __restrict__ w_v,
                      const float* __restrict__ w_state,
                      const float* __restrict__ b_state,
                      const float* __restrict__ w_out,
                      const float* __restrict__ b_out,
                      float* __restrict__ out)
{
    const int b = blockIdx.x;
    const int tid = threadIdx.x;
    const int lane = tid & 63;
    const int wv = tid >> 6;        // wave 0..3
    const int half = lane >> 5;     // half-wave 0/1
    const int la = lane & 31;       // lane within half
    const int stream = wv * 2 + half; // 8 softmax streams per block

    __shared__ __align__(16) float s_inq[3*ND];   // [curr | next | state_emb]
    __shared__ __align__(16) float s_q[ND];
    __shared__ __align__(16) float s_qk[ND];      // later reused for hn
    __shared__ __align__(16) float s_red[256];
    __shared__ __align__(16) float s_acc[8][ND];
    __shared__ __align__(16) float s_h[ND];
    __shared__ float s_ml[16];                     // m[0..7], l*w[8..15]

    const float* nb_row = node_emb + (size_t)b * NN * ND;

    // ---- input_q = [curr_emb, next_emb, state_emb] ----
    if (tid < ND) {
        const int cid = curr_id[b];
        const int nid = next_id[b];
        s_inq[tid]      = nb_row[(size_t)cid * ND + tid];
        s_inq[ND + tid] = nb_row[(size_t)nid * ND + tid];
        float se = b_state[tid];
#pragma unroll
        for (int s = 0; s < NS; ++s)
            se = fmaf(state[b*NS + s], w_state[tid*NS + s], se);
        s_inq[2*ND + tid] = se;
    }
    __syncthreads();

    // ---- q[d] = sum_e inq[e] * w_q[e,d]  (e split over block halves) ----
    {
        const int d = tid & (ND-1);
        const int h2 = tid >> 7;
        float a = 0.f;
#pragma unroll 4
        for (int e = h2*192; e < h2*192 + 192; ++e)
            a = fmaf(s_inq[e], w_q[e*ND + d], a);
        s_red[tid] = a;
    }
    __syncthreads();
    if (tid < ND) s_q[tid] = s_red[tid] + s_red[tid + ND];
    __syncthreads();

    // ---- c0 = NORM * dot(q, curr @ Wk_top) ----
    {
        const int d = tid & (ND-1);
        const int h2 = tid >> 7;
        float a = 0.f;
#pragma unroll 4
        for (int e = h2*64; e < h2*64 + 64; ++e)
            a = fmaf(s_inq[e], w_k[e*ND + d], a);
        s_red[tid] = a;
    }
    __syncthreads();
    float c0;
    {
        float v = 0.f;
        if (tid < ND) v = (s_red[tid] + s_red[tid + ND]) * s_q[tid];
#pragma unroll
        for (int m = 1; m <= 32; m <<= 1) v += __shfl_xor(v, m, 64);
        __syncthreads();
        if (lane == 0) s_red[wv] = v;   // waves 2,3 contribute 0
        __syncthreads();
        c0 = NORM * (s_red[0] + s_red[1] + s_red[2] + s_red[3]);
    }

    // ---- qk[e] = NORM * sum_d q[d] * Wk_bot[e,d]  (8 streams x 16 rows) ----
    {
        const float4 q4 = *reinterpret_cast<const float4*>(&s_q[la*4]);
#pragma unroll
        for (int j = 0; j < 16; ++j) {
            const int e = stream*16 + j;
            const float4 wr = *reinterpret_cast<const float4*>(&w_k[(ND + e)*ND + la*4]);
            float p = q4.x*wr.x + q4.y*wr.y + q4.z*wr.z + q4.w*wr.w;
            p = red32(p);
            if (la == 0) s_qk[e] = NORM * p;
        }
    }
    __syncthreads();

    // ---- main streaming loop: online softmax over nodes, 1 pass ----
    const float4 qk4 = *reinterpret_cast<const float4*>(&s_qk[la*4]);
    float m_run = -1e30f, l_run = 0.f;
    float4 acc = make_float4(0.f, 0.f, 0.f, 0.f);
    const int* mrow = mask + (size_t)b * NN;
    const int base = wv * (NN/4);

#pragma unroll 5
    for (int j = 0; j < NN/4; j += 2) {
        const int n = base + j + half;
        const float4 x = *reinterpret_cast<const float4*>(&nb_row[(size_t)n*ND + la*4]);
        const bool valid = mrow[n] != 0;
        float sd = x.x*qk4.x + x.y*qk4.y + x.z*qk4.z + x.w*qk4.w;
        sd = red32(sd);
        const float sc = valid ? (c0 + sd) : -1e38f;
        const float m_new = fmaxf(m_run, sc);
        const float escale = __expf(m_run - m_new);
        const float p = __expf(sc - m_new);
        l_run = fmaf(l_run, escale, p);
        acc.x = fmaf(acc.x, escale, p*x.x);
        acc.y = fmaf(acc.y, escale, p*x.y);
        acc.z = fmaf(acc.z, escale, p*x.z);
        acc.w = fmaf(acc.w, escale, p*x.w);
        m_run = m_new;
    }

    // ---- combine 8 streams (flash-style) ----
    if (la == 0) s_ml[stream] = m_run;
    __syncthreads();
    float m_g = s_ml[0];
#pragma unroll
    for (int i = 1; i < 8; ++i) m_g = fmaxf(m_g, s_ml[i]);
    const float wsc = __expf(m_run - m_g);
    if (la == 0) s_ml[8 + stream] = l_run * wsc;
    *reinterpret_cast<float4*>(&s_acc[stream][la*4]) =
        make_float4(acc.x*wsc, acc.y*wsc, acc.z*wsc, acc.w*wsc);
    __syncthreads();
    if (tid < ND) {
        float hv = 0.f, lg = 0.f;
#pragma unroll
        for (int i = 0; i < 8; ++i) { hv += s_acc[i][tid]; lg += s_ml[8+i]; }
        s_qk[tid] = hv / lg;   // hn = attn-weighted node emb
    }
    __syncthreads();

    // ---- h[d] = curr@Wv_top + hn@Wv_bot ----
    {
        const int d = tid & (ND-1);
        const int h2 = tid >> 7;
        const float* src = h2 ? s_qk : s_inq;            // hn : curr
        const float* wvp = w_v + (size_t)h2 * ND * ND;
        float a = 0.f;
#pragma unroll 4
        for (int e = 0; e < ND; ++e)
            a = fmaf(src[e], wvp[e*ND + d], a);
        s_red[tid] = a;
    }
    __syncthreads();
    if (tid < ND) s_h[tid] = s_red[tid] + s_red[tid + ND];
    __syncthreads();

    // ---- out[d] = dot(h, w_out[d,:]) + b_out[d] + q[d]  (8 streams x 16 rows) ----
    {
        const float4 h4 = *reinterpret_cast<const float4*>(&s_h[la*4]);
#pragma unroll
        for (int j = 0; j < 16; ++j) {
            const int dd = stream*16 + j;
            const float4 wr = *reinterpret_cast<const float4*>(&w_out[dd*ND + la*4]);
            float p = h4.x*wr.x + h4.y*wr.y + h4.z*wr.z + h4.w*wr.w;
            p = red32(p);
            if (la == 0) out[(size_t)b*ND + dd] = p + b_out[dd] + s_q[dd];
        }
    }
}

extern "C" void kernel_launch(void* const* d_in, const int* in_sizes, int n_in,
                              void* d_out, int out_size, void* d_ws, size_t ws_size,
                              hipStream_t stream) {
    const float* node_emb = (const float*)d_in[0];
    const float* state    = (const float*)d_in[1];
    const int*   curr_id  = (const int*)d_in[2];
    const int*   next_id  = (const int*)d_in[3];
    const int*   mask     = (const int*)d_in[4];
    const float* w_q     = (const float*)d_in[5];
    const float* w_k     = (const float*)d_in[6];
    const float* w_v     = (const float*)d_in[7];
    const float* w_state = (const float*)d_in[8];
    const float* b_state = (const float*)d_in[9];
    const float* w_out   = (const float*)d_in[10];
    const float* b_out   = (const float*)d_in[11];
    float* outp = (float*)d_out;

    hipLaunchKernelGGL(attn_edge_kernel, dim3(NB), dim3(256), 0, stream,
                       node_emb, state, curr_id, next_id, mask,
                       w_q, w_k, w_v, w_state, b_state, w_out, b_out, outp);
}

// Round 3
// 57.011 us; speedup vs baseline: 1.4384x; 1.4384x over previous
//
#include <hip/hip_runtime.h>

#define NB 512
#define NN 1000
#define ND 128
#define NS 8
#define THREADS 1024
#define NSTREAM 32

static constexpr float NORM = 0.088388347648318447f; // 1/sqrt(128)

__device__ __forceinline__ float red32(float v) {
#pragma unroll
    for (int m = 1; m <= 16; m <<= 1)
        v += __shfl_xor(v, m, 64);
    return v;
}

__global__ __launch_bounds__(THREADS, 8)
void attn_edge_kernel(const float* __restrict__ node_emb,
                      const float* __restrict__ state,
                      const int* __restrict__ curr_id,
                      const int* __restrict__ next_id,
                      const int* __restrict__ mask,
                      const float* __restrict__ w_q,
                      const float* __restrict__ w_k,
                      const float* __restrict__ w_v,
                      const float* __restrict__ w_state,
                      const float* __restrict__ b_state,
                      const float* __restrict__ w_out,
                      const float* __restrict__ b_out,
                      float* __restrict__ out)
{
    const int b = blockIdx.x;
    const int tid = threadIdx.x;
    const int lane = tid & 63;
    const int wv = tid >> 6;          // wave 0..15
    const int half = lane >> 5;       // half-wave 0/1
    const int la = lane & 31;         // lane within half
    const int stream = wv * 2 + half; // 32 softmax streams per block

    __shared__ __align__(16) float s_inq[3*ND];   // [curr | next | state_emb]
    __shared__ __align__(16) float s_q[ND];
    __shared__ __align__(16) float s_qk[ND];      // later reused for hn
    __shared__ __align__(16) float s_red[THREADS];
    __shared__ __align__(16) float s_acc[NSTREAM][ND];
    __shared__ __align__(16) float s_h[ND];
    __shared__ float s_ml[2*NSTREAM];             // m[0..31], l*w[32..63]

    const float* nb_row = node_emb + (size_t)b * NN * ND;

    // ---- input_q = [curr_emb, next_emb, state_emb] ----
    if (tid < ND) {
        const int cid = curr_id[b];
        const int nid = next_id[b];
        s_inq[tid]      = nb_row[(size_t)cid * ND + tid];
        s_inq[ND + tid] = nb_row[(size_t)nid * ND + tid];
        float se = b_state[tid];
#pragma unroll
        for (int s = 0; s < NS; ++s)
            se = fmaf(state[b*NS + s], w_state[tid*NS + s], se);
        s_inq[2*ND + tid] = se;
    }
    __syncthreads();

    const int d  = tid & (ND-1);
    const int ch = tid >> 7;          // chunk 0..7

    // ---- q[d] = sum_e inq[e] * w_q[e,d]  (384 rows over 8 chunks of 48) ----
    {
        float a = 0.f;
#pragma unroll 4
        for (int e = ch*48; e < ch*48 + 48; ++e)
            a = fmaf(s_inq[e], w_q[e*ND + d], a);
        s_red[tid] = a;
    }
    __syncthreads();
    if (tid < ND) {
        float a = 0.f;
#pragma unroll
        for (int c = 0; c < 8; ++c) a += s_red[tid + ND*c];
        s_q[tid] = a;
    }
    __syncthreads();

    // ---- c0 = NORM * dot(q, curr @ Wk_top)  (128 rows over 8 chunks of 16) ----
    {
        float a = 0.f;
#pragma unroll 4
        for (int e = ch*16; e < ch*16 + 16; ++e)
            a = fmaf(s_inq[e], w_k[e*ND + d], a);
        s_red[tid] = a;
    }
    __syncthreads();
    if (tid < ND) {
        float a = 0.f;
#pragma unroll
        for (int c = 0; c < 8; ++c) a += s_red[tid + ND*c];
        float v = a * s_q[tid];
#pragma unroll
        for (int m = 1; m <= 32; m <<= 1) v += __shfl_xor(v, m, 64);
        if (lane == 0) s_ml[wv] = v;     // wv = 0 or 1 here
    }
    __syncthreads();
    const float c0 = NORM * (s_ml[0] + s_ml[1]);
    __syncthreads();

    // ---- qk[e] = NORM * sum_d q[d] * Wk_bot[e,d]  (32 streams x 4 rows) ----
    {
        const float4 q4 = *reinterpret_cast<const float4*>(&s_q[la*4]);
#pragma unroll
        for (int j = 0; j < 4; ++j) {
            const int e = stream*4 + j;
            const float4 wr = *reinterpret_cast<const float4*>(&w_k[(ND + e)*ND + la*4]);
            float p = q4.x*wr.x + q4.y*wr.y + q4.z*wr.z + q4.w*wr.w;
            p = red32(p);
            if (la == 0) s_qk[e] = NORM * p;
        }
    }
    __syncthreads();

    // ---- main streaming loop: online softmax over nodes, 1 pass ----
    const float4 qk4 = *reinterpret_cast<const float4*>(&s_qk[la*4]);
    float m_run = -1e30f, l_run = 0.f;
    float4 acc = make_float4(0.f, 0.f, 0.f, 0.f);
    const int* mrow = mask + (size_t)b * NN;

    // stream s handles nodes s + 32*j, j = 0..30 (992 nodes) + tail 992..999
#pragma unroll 4
    for (int j = 0; j < 31; ++j) {
        const int n = j*NSTREAM + stream;
        const float4 x = *reinterpret_cast<const float4*>(&nb_row[(size_t)n*ND + la*4]);
        const bool valid = mrow[n] != 0;
        float sd = x.x*qk4.x + x.y*qk4.y + x.z*qk4.z + x.w*qk4.w;
        sd = red32(sd);
        const float sc = valid ? (c0 + sd) : -1e38f;
        const float m_new = fmaxf(m_run, sc);
        const float escale = __expf(m_run - m_new);
        const float p = __expf(sc - m_new);
        l_run = fmaf(l_run, escale, p);
        acc.x = fmaf(acc.x, escale, p*x.x);
        acc.y = fmaf(acc.y, escale, p*x.y);
        acc.z = fmaf(acc.z, escale, p*x.z);
        acc.w = fmaf(acc.w, escale, p*x.w);
        m_run = m_new;
    }
    if (stream < NN - 31*NSTREAM) {   // tail: nodes 992..999
        const int n = 31*NSTREAM + stream;
        const float4 x = *reinterpret_cast<const float4*>(&nb_row[(size_t)n*ND + la*4]);
        const bool valid = mrow[n] != 0;
        float sd = x.x*qk4.x + x.y*qk4.y + x.z*qk4.z + x.w*qk4.w;
        sd = red32(sd);
        const float sc = valid ? (c0 + sd) : -1e38f;
        const float m_new = fmaxf(m_run, sc);
        const float escale = __expf(m_run - m_new);
        const float p = __expf(sc - m_new);
        l_run = fmaf(l_run, escale, p);
        acc.x = fmaf(acc.x, escale, p*x.x);
        acc.y = fmaf(acc.y, escale, p*x.y);
        acc.z = fmaf(acc.z, escale, p*x.z);
        acc.w = fmaf(acc.w, escale, p*x.w);
        m_run = m_new;
    }

    // ---- combine 32 streams (flash-style) ----
    if (la == 0) s_ml[stream] = m_run;
    __syncthreads();
    float m_g = s_ml[0];
#pragma unroll
    for (int i = 1; i < NSTREAM; ++i) m_g = fmaxf(m_g, s_ml[i]);
    const float wsc = __expf(m_run - m_g);
    if (la == 0) s_ml[NSTREAM + stream] = l_run * wsc;
    *reinterpret_cast<float4*>(&s_acc[stream][la*4]) =
        make_float4(acc.x*wsc, acc.y*wsc, acc.z*wsc, acc.w*wsc);
    __syncthreads();
    if (tid < ND) {
        float hv = 0.f, lg = 0.f;
#pragma unroll
        for (int i = 0; i < NSTREAM; ++i) { hv += s_acc[i][tid]; lg += s_ml[NSTREAM+i]; }
        s_qk[tid] = hv / lg;   // hn = attn-weighted node emb
    }
    __syncthreads();

    // ---- h[d] = curr@Wv_top + hn@Wv_bot  (256 rows over 8 chunks of 32) ----
    {
        const float* src = (ch < 4) ? s_inq : (s_qk - ND);  // e<128: curr, else hn
        float a = 0.f;
#pragma unroll 4
        for (int e = ch*32; e < ch*32 + 32; ++e)
            a = fmaf(src[e], w_v[e*ND + d], a);
        s_red[tid] = a;
    }
    __syncthreads();
    if (tid < ND) {
        float a = 0.f;
#pragma unroll
        for (int c = 0; c < 8; ++c) a += s_red[tid + ND*c];
        s_h[tid] = a;
    }
    __syncthreads();

    // ---- out[d] = dot(h, w_out[d,:]) + b_out[d] + q[d]  (32 streams x 4 rows) ----
    {
        const float4 h4 = *reinterpret_cast<const float4*>(&s_h[la*4]);
#pragma unroll
        for (int j = 0; j < 4; ++j) {
            const int dd = stream*4 + j;
            const float4 wr = *reinterpret_cast<const float4*>(&w_out[dd*ND + la*4]);
            float p = h4.x*wr.x + h4.y*wr.y + h4.z*wr.z + h4.w*wr.w;
            p = red32(p);
            if (la == 0) out[(size_t)b*ND + dd] = p + b_out[dd] + s_q[dd];
        }
    }
}

extern "C" void kernel_launch(void* const* d_in, const int* in_sizes, int n_in,
                              void* d_out, int out_size, void* d_ws, size_t ws_size,
                              hipStream_t stream) {
    const float* node_emb = (const float*)d_in[0];
    const float* state    = (const float*)d_in[1];
    const int*   curr_id  = (const int*)d_in[2];
    const int*   next_id  = (const int*)d_in[3];
    const int*   mask     = (const int*)d_in[4];
    const float* w_q     = (const float*)d_in[5];
    const float* w_k     = (const float*)d_in[6];
    const float* w_v     = (const float*)d_in[7];
    const float* w_state = (const float*)d_in[8];
    const float* b_state = (const float*)d_in[9];
    const float* w_out   = (const float*)d_in[10];
    const float* b_out   = (const float*)d_in[11];
    float* outp = (float*)d_out;

    hipLaunchKernelGGL(attn_edge_kernel, dim3(NB), dim3(THREADS), 0, stream,
                       node_emb, state, curr_id, next_id, mask,
                       w_q, w_k, w_v, w_state, b_state, w_out, b_out, outp);
}